// Round 4
// baseline (3401.018 us; speedup 1.0000x reference)
//
#include <hip/hip_runtime.h>

// Chambolle-Pock ROF, 20 iterations, 4096x4096 — TWO iterations fused per
// launch, ONE strip per thread, register-resident state, minimal LDS.
//
// Block: 320 threads = 20 rows x 16 strips (8 px). Region 20x128 around a
// 16x112 interior tile. Each thread loads x_prev/x_cur/y/w/img (+ the w
// up-row halo) for its strip ONCE at stage 0, keeps them in registers
// across both fused iterations. Cross-thread data:
//   - horizontal neighbors (same row, adjacent strip) = adjacent lane in
//     the same wave -> __shfl_up/__shfl_down (no LDS, no conflicts)
//   - vertical neighbors -> LDS: sXT (f32 x_tilde), sY1 (h16 y1')
// Stages: S0 load+xt -> S1 y'(r<=18) -> S2 x_{t+1}/xt_{t+1}(r=1..18) ->
// S3 y''(r=1..17) -> S4 x_{t+2}(interior). Rounding identical to the
// unfused pipeline: x,y h16-roundtripped at each level, xt kept f32.
// Shuffle garbage at strip seams only reaches cells the interior provably
// never consumes (same cells that previously read zeroed pads).

#define MM 4096
#define NN 4096
static constexpr size_t PP = (size_t)MM * NN;

static constexpr float SIGMA_F  = 14.285714285714286f;  // 1/(7*0.01)
static constexpr float TAU_F    = 0.01f;
static constexpr float THETA_F  = 0.5f;
static constexpr float LT_F     = 0.07f;                // LAMBDA_ROF * TAU
static constexpr float INV_DEN  = 1.0f / 1.07f;

typedef _Float16 h16;
typedef __attribute__((ext_vector_type(8))) _Float16 h16x8;
typedef __attribute__((ext_vector_type(4))) float f32x4;

#define TIR 16      // interior rows per block
#define TIC 112     // interior cols per block
#define RRW 20      // region rows (tile-local -2..17)
#define XTW 132     // sXT row stride (f32): 128 + 4 pad (16B-aligned rows)
#define Y1W 136     // sY1 row stride (h16): 128 + 8 pad (16B-aligned rows)

__device__ __forceinline__ float clip1(float v) {
    return fminf(1.0f, fmaxf(-1.0f, v));
}

template<bool H>
__device__ __forceinline__ void gld8(const void* __restrict__ p, long idx, bool ok, float* o) {
    if (!ok) {
        #pragma unroll
        for (int e = 0; e < 8; ++e) o[e] = 0.f;
        return;
    }
    if constexpr (H) {
        h16x8 v = *reinterpret_cast<const h16x8*>(reinterpret_cast<const h16*>(p) + idx);
        #pragma unroll
        for (int e = 0; e < 8; ++e) o[e] = (float)v[e];
    } else {
        const float* q = reinterpret_cast<const float*>(p) + idx;
        f32x4 a = *reinterpret_cast<const f32x4*>(q);
        f32x4 b = *reinterpret_cast<const f32x4*>(q + 4);
        o[0]=a.x;o[1]=a.y;o[2]=a.z;o[3]=a.w;o[4]=b.x;o[5]=b.y;o[6]=b.z;o[7]=b.w;
    }
}

// packed (h16) load; f32 source is rounded to h16 (matches prior LDS-staged bits)
template<bool H>
__device__ __forceinline__ h16x8 gldp8(const void* __restrict__ p, long idx, bool ok) {
    h16x8 v;
    if (ok) {
        if constexpr (H) {
            v = *reinterpret_cast<const h16x8*>(reinterpret_cast<const h16*>(p) + idx);
        } else {
            const float* q = reinterpret_cast<const float*>(p) + idx;
            f32x4 a = *reinterpret_cast<const f32x4*>(q);
            f32x4 b = *reinterpret_cast<const f32x4*>(q + 4);
            v[0]=(h16)a.x; v[1]=(h16)a.y; v[2]=(h16)a.z; v[3]=(h16)a.w;
            v[4]=(h16)b.x; v[5]=(h16)b.y; v[6]=(h16)b.z; v[7]=(h16)b.w;
        }
    } else {
        #pragma unroll
        for (int e = 0; e < 8; ++e) v[e] = (h16)0.f;
    }
    return v;
}

__device__ __forceinline__ void lds8h(const h16* p, float* o) {
    h16x8 v = *reinterpret_cast<const h16x8*>(p);
    #pragma unroll
    for (int e = 0; e < 8; ++e) o[e] = (float)v[e];
}
__device__ __forceinline__ void lds8f(const float* p, float* o) {
    f32x4 a = *reinterpret_cast<const f32x4*>(p);
    f32x4 b = *reinterpret_cast<const f32x4*>(p + 4);
    o[0]=a.x;o[1]=a.y;o[2]=a.z;o[3]=a.w;o[4]=b.x;o[5]=b.y;o[6]=b.z;o[7]=b.w;
}

// MODE: 0 = first (y/w/img read f32; emits w_h/img_h), 1 = mid, 2 = last.
template<int MODE, bool WH, bool IH>
__global__ __launch_bounds__(320, 8)
void pd2(const h16* __restrict__ xprev, const h16* __restrict__ xcur,
         const void* __restrict__ yin, const void* __restrict__ w,
         const void* __restrict__ img,
         h16* __restrict__ xo1, h16* __restrict__ xo2, h16* __restrict__ yo,
         h16* __restrict__ w_h, h16* __restrict__ img_h,
         float* __restrict__ out)
{
    constexpr bool FIRST = (MODE == 0);
    constexpr bool LAST  = (MODE == 2);
    constexpr bool WRH = (!FIRST) && WH;   // w reads are half
    constexpr bool IRH = (!FIRST) && IH;   // img reads are half

    __shared__ float sXT[RRW][XTW];
    __shared__ h16   sY1[RRW][Y1W];

    const int tid = threadIdx.x;
    const int r = tid >> 4;            // 0..19
    const int s = tid & 15;            // 0..15
    const int l = 8 * s;               // region col of strip start
    const int gi  = blockIdx.y * TIR - 2 + r;
    const int gj0 = blockIdx.x * TIC - 8 + l;
    const long idx = (long)gi * NN + gj0;
    const bool okc = (gj0 >= 0) & (gj0 < NN);
    const bool ok  = (gi >= 0) & (gi < MM) & okc;
    const bool okU = (gi >= 1) & (gi <= MM) & okc;   // row gi-1 in range
    const bool notbot = gi < MM - 1;
    const bool interior = (r >= 2) & (r <= 17) & (s >= 1) & (s <= 14) & (gj0 < NN);

    float xcv[8], y0v[8], y1v[8], w0v[8], w1v[8], gim[8], xtv[8];
    h16x8 w1Up;   // w1 at row gi-1 (packed h16; rounded from f32 in MODE0)

    // ---------------- Stage 0: ALL global loads (single latency exposure)
    if constexpr (FIRST) {
        gld8<false>(img, idx, ok, gim);
        gld8<false>(yin, idx, ok, y0v);
        gld8<false>(yin, (long)PP + idx, ok, y1v);
        gld8<false>(w, idx, ok, w0v);
        gld8<false>(w, (long)PP + idx, ok, w1v);
        w1Up = gldp8<false>(w, (long)PP + idx - NN, okU);
        #pragma unroll
        for (int e = 0; e < 8; ++e) { xcv[e] = gim[e]; xtv[e] = gim[e]; }  // x0 = xt0 = img
    } else {
        float xpv[8];
        gld8<true>(xprev, idx, ok, xpv);
        gld8<true>(xcur,  idx, ok, xcv);
        gld8<IRH>(img, idx, ok, gim);
        gld8<true>(yin, idx, ok, y0v);
        gld8<true>(yin, (long)PP + idx, ok, y1v);
        gld8<WRH>(w, idx, ok, w0v);
        gld8<WRH>(w, (long)PP + idx, ok, w1v);
        w1Up = gldp8<WRH>(w, (long)PP + idx - NN, okU);
        #pragma unroll
        for (int e = 0; e < 8; ++e) xtv[e] = fmaf(THETA_F, xcv[e] - xpv[e], xcv[e]);
    }

    #pragma unroll
    for (int e = 0; e < 8; ++e) sXT[r][l + e] = xtv[e];

    if constexpr (FIRST && WH) {
        if (interior) {
            h16x8 t0, t1;
            #pragma unroll
            for (int e = 0; e < 8; ++e) { t0[e] = (h16)w0v[e]; t1[e] = (h16)w1v[e]; }
            *reinterpret_cast<h16x8*>(&w_h[idx]) = t0;
            *reinterpret_cast<h16x8*>(&w_h[PP + idx]) = t1;
        }
    }
    if constexpr (FIRST && IH) {
        if (interior) {
            h16x8 tg;
            #pragma unroll
            for (int e = 0; e < 8; ++e) tg[e] = (h16)gim[e];
            *reinterpret_cast<h16x8*>(&img_h[idx]) = tg;
        }
    }
    // left w halo: element 7 of the lane to the left (same row, same wave)
    const float w0Ls = __shfl_up(w0v[7], 1);
    __syncthreads();

    // ---------------- Stage 1: y' for rows 0..18
    {
        const float xtR = __shfl_down(xtv[0], 1);   // strip-right neighbor
        if (r <= 18) {
            float xtD[8];
            lds8f(&sXT[r + 1][l], xtD);
            h16x8 t1;
            #pragma unroll
            for (int e = 0; e < 8; ++e) {
                const float xr = (e < 7) ? xtv[e + 1] : xtR;
                const float gx = (gj0 + e < NN - 1) ? (xr - xtv[e]) : 0.f;
                const float gy = notbot ? (xtD[e] - xtv[e]) : 0.f;
                const h16 t0 = (h16)clip1(fmaf(SIGMA_F * gx, w0v[e], y0v[e]));
                t1[e] = (h16)clip1(fmaf(SIGMA_F * gy, w1v[e], y1v[e]));
                y0v[e] = (float)t0;
                y1v[e] = (float)t1[e];
            }
            *reinterpret_cast<h16x8*>(&sY1[r][l]) = t1;
        }
    }
    __syncthreads();

    // ---------------- Stage 2: x_{t+1} + xt_{t+1} for rows 1..18
    {
        const float y0Ls = __shfl_up(y0v[7], 1);
        if (r >= 1 && r <= 18) {
            float y1U[8];
            lds8h(&sY1[r - 1][l], y1U);
            float hh[8];
            #pragma unroll
            for (int e = 0; e < 8; ++e)
                hh[e] = (gj0 + e < NN - 1) ? w0v[e] * y0v[e] : 0.f;
            float dh[8];
            dh[0] = hh[0] - ((s == 0) ? 0.f : w0Ls * y0Ls);
            #pragma unroll
            for (int e = 1; e < 8; ++e) dh[e] = hh[e] - hh[e - 1];
            h16x8 xh;
            #pragma unroll
            for (int e = 0; e < 8; ++e) {
                const float vC = notbot ? w1v[e] * y1v[e] : 0.f;
                const float vU = (float)w1Up[e] * y1U[e];
                const float xv = (xcv[e] + TAU_F * (dh[e] + vC - vU) + LT_F * gim[e]) * INV_DEN;
                const h16 hx = (h16)xv;
                const float xvh = (float)hx;      // half-rounded, as unfused pipeline
                xh[e] = hx;
                xtv[e] = fmaf(THETA_F, xvh - xcv[e], xvh);
                xcv[e] = xvh;
            }
            #pragma unroll
            for (int e = 0; e < 8; ++e) sXT[r][l + e] = xtv[e];
            if constexpr (!LAST) {
                if (interior) *reinterpret_cast<h16x8*>(&xo1[idx]) = xh;
            }
        }
    }
    __syncthreads();

    // ---------------- Stage 3: y'' for rows 1..17
    {
        const float xtR = __shfl_down(xtv[0], 1);
        if (r >= 1 && r <= 17) {
            float xtD[8];
            lds8f(&sXT[r + 1][l], xtD);
            h16x8 t0, t1;
            #pragma unroll
            for (int e = 0; e < 8; ++e) {
                const float xr = (e < 7) ? xtv[e + 1] : xtR;
                const float gx = (gj0 + e < NN - 1) ? (xr - xtv[e]) : 0.f;
                const float gy = notbot ? (xtD[e] - xtv[e]) : 0.f;
                t0[e] = (h16)clip1(fmaf(SIGMA_F * gx, w0v[e], y0v[e]));
                t1[e] = (h16)clip1(fmaf(SIGMA_F * gy, w1v[e], y1v[e]));
                y0v[e] = (float)t0[e];
                y1v[e] = (float)t1[e];
            }
            *reinterpret_cast<h16x8*>(&sY1[r][l]) = t1;
            if constexpr (!LAST) {
                if (interior) {
                    *reinterpret_cast<h16x8*>(&yo[idx]) = t0;
                    *reinterpret_cast<h16x8*>(&yo[PP + idx]) = t1;
                }
            }
        }
    }
    __syncthreads();

    // ---------------- Stage 4: x_{t+2} on the interior
    {
        const float y0Ls = __shfl_up(y0v[7], 1);
        if (interior) {
            float y1U[8];
            lds8h(&sY1[r - 1][l], y1U);
            float hh[8];
            #pragma unroll
            for (int e = 0; e < 8; ++e)
                hh[e] = (gj0 + e < NN - 1) ? w0v[e] * y0v[e] : 0.f;
            float dh[8];
            dh[0] = hh[0] - w0Ls * y0Ls;       // interior => s>=1
            #pragma unroll
            for (int e = 1; e < 8; ++e) dh[e] = hh[e] - hh[e - 1];
            if constexpr (!LAST) {
                h16x8 xh;
                #pragma unroll
                for (int e = 0; e < 8; ++e) {
                    const float vC = notbot ? w1v[e] * y1v[e] : 0.f;
                    const float vU = (float)w1Up[e] * y1U[e];
                    const float xv = (xcv[e] + TAU_F * (dh[e] + vC - vU) + LT_F * gim[e]) * INV_DEN;
                    xh[e] = (h16)xv;
                }
                *reinterpret_cast<h16x8*>(&xo2[idx]) = xh;
            } else {
                float o[8];
                #pragma unroll
                for (int e = 0; e < 8; ++e) {
                    const float vC = notbot ? w1v[e] * y1v[e] : 0.f;
                    const float vU = (float)w1Up[e] * y1U[e];
                    const float xv = (xcv[e] + TAU_F * (dh[e] + vC - vU) + LT_F * gim[e]) * INV_DEN;
                    o[e] = fmaf(THETA_F, xv - xcv[e], xv);   // x_tilde_20, f32
                }
                f32x4 a, b;
                a.x = o[0]; a.y = o[1]; a.z = o[2]; a.w = o[3];
                b.x = o[4]; b.y = o[5]; b.z = o[6]; b.w = o[7];
                *reinterpret_cast<f32x4*>(&out[idx]) = a;
                *reinterpret_cast<f32x4*>(&out[idx + 4]) = b;
            }
        }
    }
}

template<bool WH, bool IH>
static void run_seq(hipStream_t s, const float* img, const float* w, const float* y0,
                    h16* const* xb, h16* yA, h16* yB, h16* w_h, h16* img_h, float* out)
{
    const dim3 grid((NN + TIC - 1) / TIC, MM / TIR);   // 37 x 256
    const dim3 block(320);
    for (int k = 0; k < 10; ++k) {
        const h16* xp = xb[(2 * k + 3) & 3];
        const h16* xc = xb[(2 * k) & 3];
        h16* xo1 = xb[(2 * k + 1) & 3];
        h16* xo2 = xb[(2 * k + 2) & 3];
        const void* yin = (k == 0) ? (const void*)y0
                                   : ((k & 1) ? (const void*)yA : (const void*)yB);
        h16* yo = (k & 1) ? yB : yA;
        const void* wp = (k == 0) ? (const void*)w
                                  : (WH ? (const void*)w_h : (const void*)w);
        const void* ip = (k == 0) ? (const void*)img
                                  : (IH ? (const void*)img_h : (const void*)img);
        if (k == 0)
            pd2<0, WH, IH><<<grid, block, 0, s>>>(xp, xc, yin, wp, ip, xo1, xo2, yo, w_h, img_h, out);
        else if (k == 9)
            pd2<2, WH, IH><<<grid, block, 0, s>>>(xp, xc, yin, wp, ip, xo1, xo2, yo, w_h, img_h, out);
        else
            pd2<1, WH, IH><<<grid, block, 0, s>>>(xp, xc, yin, wp, ip, xo1, xo2, yo, w_h, img_h, out);
    }
}

extern "C" void kernel_launch(void* const* d_in, const int* in_sizes, int n_in,
                              void* d_out, int out_size, void* d_ws, size_t ws_size,
                              hipStream_t stream) {
    const float* img = (const float*)d_in[0];   // [1,M,N]
    const float* w   = (const float*)d_in[1];   // [2,M,N]
    const float* y0  = (const float*)d_in[2];   // [2,M,N]

    h16* base = (h16*)d_ws;
    h16* xb[4] = { base, base + PP, base + 2 * PP, base + 3 * PP };
    h16* yA = base + 4 * PP;                    // 2 planes

    const size_t planes = ws_size / (PP * sizeof(h16));
    const bool WH = planes >= 8;                          // w as half (2 planes)
    const bool IH = (planes >= 9) || (planes == 7);       // img as half (1 plane)
    h16* w_h   = WH ? base + 6 * PP : nullptr;
    h16* img_h = IH ? (WH ? base + 8 * PP : base + 6 * PP) : nullptr;

    h16* yB = (h16*)d_out;                      // 2 half planes == out_size f32 bytes
    float* out = (float*)d_out;

    if (WH && IH)      run_seq<true,  true >(stream, img, w, y0, xb, yA, yB, w_h, img_h, out);
    else if (WH)       run_seq<true,  false>(stream, img, w, y0, xb, yA, yB, w_h, img_h, out);
    else if (IH)       run_seq<false, true >(stream, img, w, y0, xb, yA, yB, w_h, img_h, out);
    else               run_seq<false, false>(stream, img, w, y0, xb, yA, yB, w_h, img_h, out);
}